// Round 2
// baseline (730.243 us; speedup 1.0000x reference)
//
#include <hip/hip_runtime.h>
#include <cstdint>

// out[b,s,o] = sum_k in[b,s,k] * lut[w[o,k]] + bias[o]
// GEMM: M=8192, N=4096, K=4096, fp32 out. f16 MFMA path.
// R2 change: LDS tiles stored in MFMA-FRAGMENT ORDER (16B chunk = one lane's
// half8 frag). Staging gathers on the global side; all ds_read_b128 become
// base + lane*16 (linear, conflict-free). R1 had 1.0e8 conflict cycles from
// column-determined banks (row stride 128B = 32 banks).

static constexpr int Md = 8192;
static constexpr int Nd = 4096;
static constexpr int Kd = 4096;

typedef _Float16 half8 __attribute__((ext_vector_type(8)));
typedef float f32x4 __attribute__((ext_vector_type(4)));

__device__ __forceinline__ void async_copy16(const _Float16* g, _Float16* l) {
  __builtin_amdgcn_global_load_lds((const __attribute__((address_space(1))) void*)g,
                                   (__attribute__((address_space(3))) void*)l, 16, 0, 0);
}

// ---- convert input fp32 -> fp16, 8 elems/thread ----
__global__ __launch_bounds__(256) void cvt_a(const float* __restrict__ in,
                                             _Float16* __restrict__ out) {
  const size_t i = (size_t)blockIdx.x * 256 + threadIdx.x;
  const float4 x = ((const float4*)in)[2 * i];
  const float4 y = ((const float4*)in)[2 * i + 1];
  half8 h;
  h[0] = (_Float16)x.x; h[1] = (_Float16)x.y; h[2] = (_Float16)x.z; h[3] = (_Float16)x.w;
  h[4] = (_Float16)y.x; h[5] = (_Float16)y.y; h[6] = (_Float16)y.z; h[7] = (_Float16)y.w;
  *(half8*)(out + 8 * i) = h;
}

// ---- dequant weight idx -> fp16 via LDS-cached 256-entry LUT ----
__global__ __launch_bounds__(256) void dequant_b(const int* __restrict__ w,
                                                 const float* __restrict__ lut,
                                                 _Float16* __restrict__ out) {
  __shared__ float slut[256];
  slut[threadIdx.x] = lut[threadIdx.x];
  __syncthreads();
  const size_t i = (size_t)blockIdx.x * 256 + threadIdx.x;
  const int4 a = ((const int4*)w)[2 * i];
  const int4 b = ((const int4*)w)[2 * i + 1];
  half8 h;
  h[0] = (_Float16)slut[a.x]; h[1] = (_Float16)slut[a.y];
  h[2] = (_Float16)slut[a.z]; h[3] = (_Float16)slut[a.w];
  h[4] = (_Float16)slut[b.x]; h[5] = (_Float16)slut[b.y];
  h[6] = (_Float16)slut[b.z]; h[7] = (_Float16)slut[b.w];
  *(half8*)(out + 8 * i) = h;
}

// ---- C[M][N] = A[M][K] * Bt[N][K]^T + bias ----
// 128x128 tile, BK=64, 4 waves (2x2), 4x4 MFMA 16x16x32 per wave.
// LDS layout: As[sel][lane] 16B chunks, sel = wm*8 + i*2 + ks (0..15).
// Chunk(sel,lane) = A[tile_row: wm*64+i*16+(lane&15)][k: ks*32+(lane>>4)*8 ..+8]
__global__ __launch_bounds__(256) void gemm_f16(const _Float16* __restrict__ A,
                                                const _Float16* __restrict__ Bt,
                                                const float* __restrict__ bias,
                                                float* __restrict__ C) {
  __shared__ __align__(16) _Float16 As[16 * 512];  // 16 KiB, fragment order
  __shared__ __align__(16) _Float16 Bs[16 * 512];

  const int tid = threadIdx.x;
  const int lane = tid & 63;
  const int wave = tid >> 6;
  const int wm = wave >> 1;
  const int wn = wave & 1;
  const int bm = blockIdx.x, bn = blockIdx.y;

  const int l15 = lane & 15;
  const int l4 = lane >> 4;

  // staging: round r, wave w stages chunk group sel = r*4 + wave.
  // global src: row = swm*64 + si*16 + (lane&15), col = sks*32 + (lane>>4)*8
  size_t src_off[4];
  int lds_off[4];
#pragma unroll
  for (int r = 0; r < 4; ++r) {
    const int sel = r * 4 + wave;
    const int swm = sel >> 3, si = (sel >> 1) & 3, sks = sel & 1;
    const int grow = swm * 64 + si * 16 + l15;
    const int gcol = sks * 32 + l4 * 8;
    src_off[r] = (size_t)grow * Kd + gcol;
    lds_off[r] = sel * 512 + lane * 8;
  }

  const _Float16* Ag = A + (size_t)bm * 128 * Kd;
  const _Float16* Bg = Bt + (size_t)bn * 128 * Kd;

  f32x4 acc[4][4] = {};

  for (int kt = 0; kt < Kd / 64; ++kt) {
#pragma unroll
    for (int r = 0; r < 4; ++r) {
      async_copy16(Ag + src_off[r], As + lds_off[r]);
      async_copy16(Bg + src_off[r], Bs + lds_off[r]);
    }
    Ag += 64;
    Bg += 64;
    __syncthreads();
#pragma unroll
    for (int ks = 0; ks < 2; ++ks) {
      half8 a[4], b[4];
#pragma unroll
      for (int i = 0; i < 4; ++i)
        a[i] = *(const half8*)(As + (wm * 8 + i * 2 + ks) * 512 + lane * 8);
#pragma unroll
      for (int j = 0; j < 4; ++j)
        b[j] = *(const half8*)(Bs + (wn * 8 + j * 2 + ks) * 512 + lane * 8);
#pragma unroll
      for (int i = 0; i < 4; ++i)
#pragma unroll
        for (int j = 0; j < 4; ++j)
          acc[i][j] = __builtin_amdgcn_mfma_f32_16x16x32_f16(a[i], b[j], acc[i][j], 0, 0, 0);
    }
    __syncthreads();
  }

  // epilogue: C/D layout col = lane&15, row = (lane>>4)*4 + reg
  const int fr = l15;
  const int fq = l4;
  const int ccol0 = bn * 128 + wn * 64 + fr;
  const int crow0 = bm * 128 + wm * 64 + fq * 4;
  float bv[4];
#pragma unroll
  for (int j = 0; j < 4; ++j) bv[j] = bias[ccol0 + j * 16];
#pragma unroll
  for (int i = 0; i < 4; ++i) {
#pragma unroll
    for (int r = 0; r < 4; ++r) {
      float* cp = C + (size_t)(crow0 + i * 16 + r) * Nd + ccol0;
#pragma unroll
      for (int j = 0; j < 4; ++j) cp[j * 16] = acc[i][j][r] + bv[j];
    }
  }
}

extern "C" void kernel_launch(void* const* d_in, const int* in_sizes, int n_in,
                              void* d_out, int out_size, void* d_ws, size_t ws_size,
                              hipStream_t stream) {
  const float* inp  = (const float*)d_in[0];
  const float* lut  = (const float*)d_in[1];
  const int*   wgt  = (const int*)d_in[2];
  const float* bias = (const float*)d_in[3];
  float* out = (float*)d_out;

  _Float16* Ah = (_Float16*)d_ws;
  _Float16* Bh = (_Float16*)d_ws + (size_t)Md * Kd;

  cvt_a<<<(Md * (size_t)Kd) / (8 * 256), 256, 0, stream>>>(inp, Ah);
  dequant_b<<<((size_t)Nd * Kd) / (8 * 256), 256, 0, stream>>>(wgt, lut, Bh);

  dim3 grid(Md / 128, Nd / 128);
  gemm_f16<<<grid, 256, 0, stream>>>(Ah, Bh, bias, out);
}

// Round 3
// 567.758 us; speedup vs baseline: 1.2862x; 1.2862x over previous
//
#include <hip/hip_runtime.h>
#include <cstdint>

// out[b,s,o] = sum_k in[b,s,k] * lut[w[o,k]] + bias[o]
// GEMM: M=8192, N=4096, K=4096, fp32 out. f16 MFMA path.
// R3: R1 staging (coalesced 128B row segments, global_load_lds w=16) + XOR
// chunk swizzle: LDS slot (row,c) holds global chunk (row, c^(row&7)).
// Fragment ds_read_b128 then spans all 32 banks (8 words/bank = min).
// R1: conflicts 1e8, 437us. R2: conflicts 0 but 64B segments, 515us.

static constexpr int Md = 8192;
static constexpr int Nd = 4096;
static constexpr int Kd = 4096;

typedef _Float16 half8 __attribute__((ext_vector_type(8)));
typedef float f32x4 __attribute__((ext_vector_type(4)));

__device__ __forceinline__ void async_copy16(const _Float16* g, _Float16* l) {
  __builtin_amdgcn_global_load_lds((const __attribute__((address_space(1))) void*)g,
                                   (__attribute__((address_space(3))) void*)l, 16, 0, 0);
}

// ---- convert input fp32 -> fp16, 8 elems/thread ----
__global__ __launch_bounds__(256) void cvt_a(const float* __restrict__ in,
                                             _Float16* __restrict__ out) {
  const size_t i = (size_t)blockIdx.x * 256 + threadIdx.x;
  const float4 x = ((const float4*)in)[2 * i];
  const float4 y = ((const float4*)in)[2 * i + 1];
  half8 h;
  h[0] = (_Float16)x.x; h[1] = (_Float16)x.y; h[2] = (_Float16)x.z; h[3] = (_Float16)x.w;
  h[4] = (_Float16)y.x; h[5] = (_Float16)y.y; h[6] = (_Float16)y.z; h[7] = (_Float16)y.w;
  *(half8*)(out + 8 * i) = h;
}

// ---- dequant weight idx -> fp16 via LDS-cached 256-entry LUT ----
__global__ __launch_bounds__(256) void dequant_b(const int* __restrict__ w,
                                                 const float* __restrict__ lut,
                                                 _Float16* __restrict__ out) {
  __shared__ float slut[256];
  slut[threadIdx.x] = lut[threadIdx.x];
  __syncthreads();
  const size_t i = (size_t)blockIdx.x * 256 + threadIdx.x;
  const int4 a = ((const int4*)w)[2 * i];
  const int4 b = ((const int4*)w)[2 * i + 1];
  half8 h;
  h[0] = (_Float16)slut[a.x]; h[1] = (_Float16)slut[a.y];
  h[2] = (_Float16)slut[a.z]; h[3] = (_Float16)slut[a.w];
  h[4] = (_Float16)slut[b.x]; h[5] = (_Float16)slut[b.y];
  h[6] = (_Float16)slut[b.z]; h[7] = (_Float16)slut[b.w];
  *(half8*)(out + 8 * i) = h;
}

// ---- C[M][N] = A[M][K] * Bt[N][K]^T + bias ----
// 128x128 tile, BK=64, 4 waves (2x2), 4x4 MFMA 16x16x32 per wave.
__global__ __launch_bounds__(256) void gemm_f16(const _Float16* __restrict__ A,
                                                const _Float16* __restrict__ Bt,
                                                const float* __restrict__ bias,
                                                float* __restrict__ C) {
  __shared__ __align__(16) _Float16 As[128 * 64];  // [row][8 chunks of 16B], XOR-swizzled
  __shared__ __align__(16) _Float16 Bs[128 * 64];

  const int tid = threadIdx.x;
  const int lane = tid & 63;
  const int wave = tid >> 6;
  const int wm = wave >> 1;
  const int wn = wave & 1;
  const int bm = blockIdx.x, bn = blockIdx.y;

  // staging: 256 thr x 16B = 32 rows/round; 4 rounds. Row = 128B contiguous
  // segment; lanes within a row permuted by XOR (coalescing unaffected).
  const int sr = wave * 8 + (lane >> 3);                 // 0..31
  const int gc = ((lane & 7) ^ (sr & 7)) * 8;            // swizzled global chunk
  const _Float16* ag = A  + (size_t)(bm * 128 + sr) * Kd + gc;
  const _Float16* bg = Bt + (size_t)(bn * 128 + sr) * Kd + gc;
  _Float16* al = As + sr * 64 + (lane & 7) * 8;          // wave-uniform + lane*16B
  _Float16* bl = Bs + sr * 64 + (lane & 7) * 8;

  // fragment: global chunk kc = ks*4+fq of row (wm*64+i*16+fr) sits at
  // LDS slot kc ^ (fr&7)  (row bits above 3 vanish mod 8).
  const int fr = lane & 15;
  const int fq = lane >> 4;
  const int e = fr & 7;
  const int slot0 = (fq ^ e) * 8;        // ks = 0
  const int slot1 = ((4 | fq) ^ e) * 8;  // ks = 1
  const _Float16* afp = As + (wm * 64 + fr) * 64;
  const _Float16* bfp = Bs + (wn * 64 + fr) * 64;

  f32x4 acc[4][4] = {};

  for (int kt = 0; kt < Kd / 64; ++kt) {
#pragma unroll
    for (int r = 0; r < 4; ++r) {
      async_copy16(ag + (size_t)r * 32 * Kd, al + r * 2048);
      async_copy16(bg + (size_t)r * 32 * Kd, bl + r * 2048);
    }
    ag += 64;
    bg += 64;
    __syncthreads();
#pragma unroll
    for (int ks = 0; ks < 2; ++ks) {
      const int slot = ks ? slot1 : slot0;
      half8 a[4], b[4];
#pragma unroll
      for (int i = 0; i < 4; ++i) a[i] = *(const half8*)(afp + i * 16 * 64 + slot);
#pragma unroll
      for (int j = 0; j < 4; ++j) b[j] = *(const half8*)(bfp + j * 16 * 64 + slot);
#pragma unroll
      for (int i = 0; i < 4; ++i)
#pragma unroll
        for (int j = 0; j < 4; ++j)
          acc[i][j] = __builtin_amdgcn_mfma_f32_16x16x32_f16(a[i], b[j], acc[i][j], 0, 0, 0);
    }
    __syncthreads();
  }

  // epilogue: C/D layout col = lane&15, row = (lane>>4)*4 + reg
  const int ccol0 = bn * 128 + wn * 64 + fr;
  const int crow0 = bm * 128 + wm * 64 + fq * 4;
  float bv[4];
#pragma unroll
  for (int j = 0; j < 4; ++j) bv[j] = bias[ccol0 + j * 16];
#pragma unroll
  for (int i = 0; i < 4; ++i) {
#pragma unroll
    for (int r = 0; r < 4; ++r) {
      float* cp = C + (size_t)(crow0 + i * 16 + r) * Nd + ccol0;
#pragma unroll
      for (int j = 0; j < 4; ++j) cp[j * 16] = acc[i][j][r] + bv[j];
    }
  }
}

extern "C" void kernel_launch(void* const* d_in, const int* in_sizes, int n_in,
                              void* d_out, int out_size, void* d_ws, size_t ws_size,
                              hipStream_t stream) {
  const float* inp  = (const float*)d_in[0];
  const float* lut  = (const float*)d_in[1];
  const int*   wgt  = (const int*)d_in[2];
  const float* bias = (const float*)d_in[3];
  float* out = (float*)d_out;

  _Float16* Ah = (_Float16*)d_ws;
  _Float16* Bh = (_Float16*)d_ws + (size_t)Md * Kd;

  cvt_a<<<(Md * (size_t)Kd) / (8 * 256), 256, 0, stream>>>(inp, Ah);
  dequant_b<<<((size_t)Nd * Kd) / (8 * 256), 256, 0, stream>>>(wgt, lut, Bh);

  dim3 grid(Md / 128, Nd / 128);
  gemm_f16<<<grid, 256, 0, stream>>>(Ah, Bh, bias, out);
}